// Round 12
// baseline (661.579 us; speedup 1.0000x reference)
//
#include <hip/hip_runtime.h>
#include <math.h>

typedef __attribute__((ext_vector_type(8))) short short8;
typedef __attribute__((ext_vector_type(4))) short short4v;
typedef __attribute__((ext_vector_type(8))) unsigned short u16x8;
typedef __attribute__((ext_vector_type(4))) float f32x4;

#define NN 512
#define JT 32
#define STR 136            // LDS row stride (bf16 elems): 272B, 16B-aligned, 2-way bank aliasing only
#define BUFSZ (JT * STR)   // 4352 ushorts = 8704 B per buffer
#define E2S 36             // stride of small edge2 output buffer

#define TOT_W 106496       // prepacked weight elements (bf16)

// Native bf16 conversion (RNE) — lowers to gfx950 HW cvt.
__device__ __forceinline__ unsigned short f2b(float x) {
    return __builtin_bit_cast(unsigned short, (__bf16)x);
}
__device__ __forceinline__ float b2f(unsigned short v) {
    return __uint_as_float(((unsigned int)v) << 16);
}
__device__ __forceinline__ float silu_f(float v) { return v / (1.f + __expf(-v)); }

// 512-thread-safe dual half reduction: threads 0..255 hold data (two independent
// 128-value sums: t<128 -> A, 128<=t<256 -> B); threads >=256 just hit barriers.
__device__ __forceinline__ float half_sum512(float v, float* s_red, int t) {
    if (t < 256) s_red[t] = v;
    __syncthreads();
    int tt = t & 127;
    for (int s = 64; s > 0; s >>= 1) {
        if (t < 256 && tt < s) s_red[t] += s_red[t + s];
        __syncthreads();
    }
    float r = (t < 256) ? s_red[t & 128] : 0.f;
    __syncthreads();
    return r;
}

// Cross-tile staging prefetch (T14): load tile j0n's h/e slice into registers.
// half 0 threads own h rows; half 1 threads own e rows (A: sub<4, B: sub>=4).
__device__ __forceinline__ void preload_tile(int half, int sub, int jrow, int j0n,
                                             int b, int biA, int biB,
                                             const float* __restrict__ h,
                                             const float* __restrict__ e,
                                             f32x4& r0, f32x4& r1) {
    int jj = j0n + jrow;
    if (half == 0) {
        const f32x4* hp = (const f32x4*)(h + ((size_t)(b * NN + jj)) * 64 + sub * 8);
        r0 = hp[0];
        r1 = hp[1];
    } else if (sub < 4) {
        const f32x4* ea = (const f32x4*)(e + ((size_t)biA * NN + jj) * 32 + sub * 8);
        r0 = __builtin_nontemporal_load(ea);
        r1 = __builtin_nontemporal_load(ea + 1);
    } else {
        const f32x4* eb = (const f32x4*)(e + ((size_t)biB * NN + jj) * 32 + (sub - 4) * 8);
        r0 = __builtin_nontemporal_load(eb);
        r1 = __builtin_nontemporal_load(eb + 1);
    }
}

// -------- weight prepack: fp32 -> bf16 A-operand fragments --------
// frag element: ws[(((ft*nK+ks)*64 + lane)*8 + jj)] = W[k][f],
//   k = ks*32 + (lane>>4)*8 + jj ; f = ft*16 + (lane&15)
__device__ __forceinline__ void frag_kf(int loc, int nK, int& k, int& f) {
    int jj = loc & 7;
    int lane = (loc >> 3) & 63;
    int fs = loc >> 9;
    int ks = fs % nK;
    int ft = fs / nK;
    k = ks * 32 + ((lane >> 4) << 3) + jj;
    f = ft * 16 + (lane & 15);
}

extern "C" __global__ void prepack_w(const float* __restrict__ msg_W1, const float* __restrict__ msg_W2,
                                     const float* __restrict__ msg_W3, const float* __restrict__ val_W,
                                     const float* __restrict__ attn_W1, const float* __restrict__ coord_W1,
                                     const float* __restrict__ edge_W1, const float* __restrict__ edge_W2,
                                     unsigned short* __restrict__ ws) {
    int idx = blockIdx.x * 256 + threadIdx.x;
    if (idx >= TOT_W) return;
    float v;
    int k, f;
    if (idx < 16384) {            // G1: msg_input-without-h_i @ W1 : rows [h_j(64)|e(32)|dist(1)|pad]
        frag_kf(idx, 4, k, f);
        v = (k <= 96) ? msg_W1[(64 + k) * 128 + f] : 0.f;
    } else if (idx < 32768) {     // G2
        frag_kf(idx - 16384, 4, k, f);
        v = msg_W2[k * 128 + f];
    } else if (idx < 49152) {     // G3
        frag_kf(idx - 32768, 4, k, f);
        v = msg_W3[k * 128 + f];
    } else if (idx < 65536) {     // val
        frag_kf(idx - 49152, 4, k, f);
        v = val_W[k * 128 + f];
    } else if (idx < 81920) {     // ac = [attn_W1 | coord_W1]
        frag_kf(idx - 65536, 4, k, f);
        v = (f < 64) ? attn_W1[k * 64 + f] : coord_W1[k * 64 + (f - 64)];
    } else if (idx < 102400) {    // edge_W1: ks 0..3 = msg part (rows 32..159), ks 4 = e part (rows 0..31)
        frag_kf(idx - 81920, 5, k, f);
        v = (k < 128) ? edge_W1[(32 + k) * 128 + f] : edge_W1[(k - 128) * 128 + f];
    } else {                      // edge_W2 (32 out)
        frag_kf(idx - 102400, 4, k, f);
        v = edge_W2[k * 32 + f];
    }
    ws[idx] = f2b(v);
}

// -------- MFMA helpers (one 16-wide f-tile per wave) --------
struct Frag1 { f32x4 a[2]; };   // two j-halves

__device__ __forceinline__ short8 wfrag(const unsigned short* base, int nK, int ft, int ks, int lane) {
    return *(const short8*)(base + (((ft * nK + ks) << 9) + (lane << 3)));
}

__device__ __forceinline__ void initF1(Frag1& F, const float* bias, int ft, int lane) {
    int q = lane >> 4;
    f32x4 bv = *(const f32x4*)(bias + ft * 16 + q * 4);
    F.a[0] = bv; F.a[1] = bv;
}

__device__ __forceinline__ void ldb(const unsigned short* B, int kcol, int lane, short8& b0, short8& b1) {
    int q8 = ((lane >> 4) << 3), l15 = lane & 15;
    b0 = *(const short8*)(B + l15 * STR + kcol + q8);
    b1 = *(const short8*)(B + (16 + l15) * STR + kcol + q8);
}

__device__ __forceinline__ void mfma2(Frag1& F, short8 a, short8 b0, short8 b1) {
    F.a[0] = __builtin_amdgcn_mfma_f32_16x16x32_bf16(a, b0, F.a[0], 0, 0, 0);
    F.a[1] = __builtin_amdgcn_mfma_f32_16x16x32_bf16(a, b1, F.a[1], 0, 0, 0);
}

__device__ __forceinline__ void storeF1(const Frag1& F, unsigned short* dbuf, int ft, int lane, int act) {
    int q = lane >> 4, l15 = lane & 15;
#pragma unroll
    for (int ji = 0; ji < 2; ji++) {
        int j = ji * 16 + l15;
        int f0 = ft * 16 + q * 4;
        f32x4 v = F.a[ji];
        short4v p;
#pragma unroll
        for (int r = 0; r < 4; r++) {
            float o = act ? silu_f(v[r]) : v[r];
            p[r] = (short)f2b(o);
        }
        *(short4v*)(dbuf + j * STR + f0) = p;
    }
}

// LayerNorm over 128 features (bf16 rows, fp32 math). tt in [0,256): j=tt>>3, sub=tt&7.
__device__ __forceinline__ void ln_tile(unsigned short* buf, const float* g, const float* bv, int tt) {
    int j = tt >> 3, sub = tt & 7;
    unsigned short* p = buf + j * STR + sub * 16;
    u16x8 r0 = *(u16x8*)p;
    u16x8 r1 = *(u16x8*)(p + 8);
    float v[16];
#pragma unroll
    for (int i = 0; i < 8; i++) { v[i] = b2f(r0[i]); v[8 + i] = b2f(r1[i]); }
    float sm = 0.f;
#pragma unroll
    for (int i = 0; i < 16; i++) sm += v[i];
    sm += __shfl_xor(sm, 1); sm += __shfl_xor(sm, 2); sm += __shfl_xor(sm, 4);
    float mean = sm * 0.0078125f;
    float sq = 0.f;
#pragma unroll
    for (int i = 0; i < 16; i++) { float d = v[i] - mean; sq += d * d; }
    sq += __shfl_xor(sq, 1); sq += __shfl_xor(sq, 2); sq += __shfl_xor(sq, 4);
    float rstd = rsqrtf(sq * 0.0078125f + 1e-5f);
    u16x8 o0, o1;
#pragma unroll
    for (int i = 0; i < 8; i++) {
        o0[i] = f2b((v[i] - mean) * rstd * g[sub * 16 + i] + bv[sub * 16 + i]);
        o1[i] = f2b((v[8 + i] - mean) * rstd * g[sub * 16 + 8 + i] + bv[sub * 16 + 8 + i]);
    }
    *(u16x8*)p = o0;
    *(u16x8*)(p + 8) = o1;
}

// =====================================================================
// 2 i-nodes per block, 512 threads (8 waves, ft = wave): grid 512 =
// 2 blocks/CU (66 KB LDS), 4 waves/SIMD. Round-10 structure + T14
// cross-tile prefetch: next tile's h/e staging data loaded into regs
// right after the staging barrier, hiding HBM latency under G1..fusedE.
// =====================================================================
extern "C" __global__ __launch_bounds__(512, 4)
void egnn_mfma(const float* __restrict__ h, const float* __restrict__ x, const float* __restrict__ e,
               const float* __restrict__ msg_W1, const float* __restrict__ msg_b1,
               const float* __restrict__ msg_ln_g, const float* __restrict__ msg_ln_b,
               const float* __restrict__ msg_b2, const float* __restrict__ msg_b3,
               const float* __restrict__ attn_b1, const float* __restrict__ attn_W2,
               const float* __restrict__ attn_b2, const float* __restrict__ val_b,
               const float* __restrict__ coord_b1, const float* __restrict__ coord_W2,
               const float* __restrict__ node_W1, const float* __restrict__ node_b1,
               const float* __restrict__ node_ln_g, const float* __restrict__ node_ln_b,
               const float* __restrict__ node_W2, const float* __restrict__ node_b2,
               const float* __restrict__ edge_b1, const float* __restrict__ edge_ln_g,
               const float* __restrict__ edge_ln_b, const float* __restrict__ edge_b2,
               const float* __restrict__ nn_g, const float* __restrict__ nn_b,
               const float* __restrict__ en_g, const float* __restrict__ en_b,
               const float* __restrict__ coord_scale_p,
               const unsigned short* __restrict__ wpk,
               float* __restrict__ out_h, float* __restrict__ out_x, float* __restrict__ out_e) {
    const int t = threadIdx.x;
    const int wave = t >> 6, lane = t & 63;
    const int biA = blockIdx.x * 2;
    const int biB = biA + 1;
    const int b = biA >> 9;

    __shared__ __align__(16) unsigned short smA[3 * BUFSZ];
    __shared__ __align__(16) unsigned short smB[3 * BUFSZ];
    unsigned short* B0a = smA;
    unsigned short* B1a = smA + BUFSZ;
    unsigned short* B2a = smA + 2 * BUFSZ;
    unsigned short* B0b = smB;
    unsigned short* B1b = smB + BUFSZ;
    unsigned short* B2b = smB + 2 * BUFSZ;
    __shared__ __align__(16) unsigned short s_e2a[32 * E2S];
    __shared__ __align__(16) unsigned short s_e2b[32 * E2S];

    __shared__ __align__(16) float s_bias1a[128], s_bias1b[128];
    __shared__ __align__(16) float s_b2c[128], s_b3c[128], s_bv[128], s_bac[128], s_be1[128];
    __shared__ __align__(16) float s_be2[32];
    __shared__ __align__(16) float s_mg[128], s_mb[128], s_eg[128], s_eb[128];
    __shared__ __align__(16) float s_cw2[64], s_aw2[4][64], s_ab2[4], s_eng[32], s_enb[32];
    __shared__ __align__(16) float s_lg[2][JT][4];
    __shared__ __align__(16) float s_hiA[64], s_hiB[64];

    const unsigned short* wG1 = wpk;
    const unsigned short* wG2 = wpk + 16384;
    const unsigned short* wG3 = wpk + 32768;
    const unsigned short* wV  = wpk + 49152;
    const unsigned short* wAC = wpk + 65536;
    const unsigned short* wE1 = wpk + 81920;
    const unsigned short* wE2 = wpk + 102400;

    // ---- stage params ----
    if (t < 64) s_hiA[t] = h[(size_t)biA * 64 + t];
    else if (t < 128) s_hiB[t - 64] = h[(size_t)biB * 64 + (t - 64)];
    if (t < 128) {
        s_b2c[t] = msg_b2[t]; s_b3c[t] = msg_b3[t]; s_bv[t] = val_b[t];
        s_bac[t] = (t < 64) ? attn_b1[t] : coord_b1[t - 64];
        s_be1[t] = edge_b1[t];
        s_mg[t] = msg_ln_g[t]; s_mb[t] = msg_ln_b[t];
        s_eg[t] = edge_ln_g[t]; s_eb[t] = edge_ln_b[t];
    }
    if (t < 32) { s_be2[t] = edge_b2[t]; s_eng[t] = en_g[t]; s_enb[t] = en_b[t]; }
    if (t < 64) s_cw2[t] = coord_W2[t];
    if (t < 256) { int hh = t >> 6, k = t & 63; s_aw2[hh][k] = attn_W2[k * 4 + hh]; }
    if (t < 4) s_ab2[t] = attn_b2[t];
    __syncthreads();
    // bias1' = msg_b1 + h_i @ W1[0:64]  (fp32, exact) — per i
    if (t < 256) {
        int ii = t >> 7, tt = t & 127;
        const float* hi = ii ? s_hiB : s_hiA;
        float acc = msg_b1[tt];
        for (int k = 0; k < 64; k++) acc = fmaf(hi[k], msg_W1[k * 128 + tt], acc);
        (ii ? s_bias1b : s_bias1a)[tt] = acc;
    }
    const float xiA0 = x[(size_t)biA * 2 + 0];
    const float xiA1 = x[(size_t)biA * 2 + 1];
    const float xiB0 = x[(size_t)biB * 2 + 0];
    const float xiB1 = x[(size_t)biB * 2 + 1];

    float m_run = -3e38f, l_run = 0.f, acc_run = 0.f;   // t<256 only: i=t>>7, f=t&127
    float cu_x = 0.f, cu_y = 0.f, xdn_x = 0.f, xdn_y = 0.f;

    const int l15 = lane & 15;

    // ---- staging role (fixed per thread) + tile-0 prefetch ----
    const int halfR = t >> 8, ttR = t & 255;
    const int jrowR = ttR >> 3, subR = ttR & 7;
    f32x4 pr0, pr1;
    preload_tile(halfR, subR, jrowR, 0, b, biA, biB, h, e, pr0, pr1);

#pragma unroll 1
    for (int j0 = 0; j0 < NN; j0 += JT) {
        // ---- stage from prefetched regs: half 0 -> h (+zeros), half 1 -> eA/eB ----
        {
            if (halfR == 0) {
                u16x8 o;
                o[0] = f2b(pr0[0]); o[1] = f2b(pr0[1]); o[2] = f2b(pr0[2]); o[3] = f2b(pr0[3]);
                o[4] = f2b(pr1[0]); o[5] = f2b(pr1[1]); o[6] = f2b(pr1[2]); o[7] = f2b(pr1[3]);
                *(u16x8*)(B0a + jrowR * STR + subR * 8) = o;   // h shared: only in B0a
                u16x8 z = (u16x8)0;
                if (subR > 4)       *(u16x8*)(B0a + jrowR * STR + 96 + (subR - 4) * 8) = z;  // 104..127
                else if (subR >= 1) *(u16x8*)(B0b + jrowR * STR + 96 + subR * 8) = z;        // 104..127
            } else {
                u16x8 oe;
                oe[0] = f2b(pr0[0]); oe[1] = f2b(pr0[1]); oe[2] = f2b(pr0[2]); oe[3] = f2b(pr0[3]);
                oe[4] = f2b(pr1[0]); oe[5] = f2b(pr1[1]); oe[6] = f2b(pr1[2]); oe[7] = f2b(pr1[3]);
                if (subR < 4) *(u16x8*)(B0a + jrowR * STR + 64 + subR * 8) = oe;
                else          *(u16x8*)(B0b + jrowR * STR + 64 + (subR - 4) * 8) = oe;
            }
        }
        if (t < JT) {                    // dist for i=A (these threads also own coord state for A)
            int jj = j0 + t;
            float dx = x[(size_t)(b * NN + jj) * 2 + 0] - xiA0;
            float dy = x[(size_t)(b * NN + jj) * 2 + 1] - xiA1;
            float dist = sqrtf(dx * dx + dy * dy);
            float inv = 1.f / (dist + 1e-8f);
            xdn_x = dx * inv; xdn_y = dy * inv;
            u16x8 z = (u16x8)0;
            z[0] = f2b(dist);
            *(u16x8*)(B0a + t * STR + 96) = z;                 // dist + zeros 97..103
        } else if (t >= 128 && t < 128 + JT) {   // dist for i=B
            int tb = t - 128;
            int jj = j0 + tb;
            float dx = x[(size_t)(b * NN + jj) * 2 + 0] - xiB0;
            float dy = x[(size_t)(b * NN + jj) * 2 + 1] - xiB1;
            float dist = sqrtf(dx * dx + dy * dy);
            float inv = 1.f / (dist + 1e-8f);
            xdn_x = dx * inv; xdn_y = dy * inv;
            u16x8 z = (u16x8)0;
            z[0] = f2b(dist);
            *(u16x8*)(B0b + tb * STR + 96) = z;
        }
        __syncthreads();

        // ---- issue next tile's staging loads (hide HBM latency under G1..fusedE) ----
        if (j0 + JT < NN)
            preload_tile(halfR, subR, jrowR, j0 + JT, b, biA, biB, h, e, pr0, pr1);

        // ---- G1: silu([h_j|e|dist] @ W1' + bias1') -> B1a/B1b (h-part from B0a for both) ----
        {
            Frag1 Fa, Fb;
            initF1(Fa, s_bias1a, wave, lane);
            initF1(Fb, s_bias1b, wave, lane);
#pragma unroll
            for (int ks = 0; ks < 4; ks++) {
                short8 a = wfrag(wG1, 4, wave, ks, lane);
                short8 b0, b1;
                ldb(B0a, ks * 32, lane, b0, b1);
                mfma2(Fa, a, b0, b1);
                if (ks >= 2) ldb(B0b, ks * 32, lane, b0, b1);   // e/dist region differs per i
                mfma2(Fb, a, b0, b1);
            }
            storeF1(Fa, B1a, wave, lane, 1);
            storeF1(Fb, B1b, wave, lane, 1);
        }
        __syncthreads();
        if (t < 256) ln_tile(B1a, s_mg, s_mb, t);
        else         ln_tile(B1b, s_mg, s_mb, t - 256);
        __syncthreads();

        // ---- G2: silu(B1 @ W2 + b2) -> B2a/B2b ----
        {
            Frag1 Fa, Fb;
            initF1(Fa, s_b2c, wave, lane);
            initF1(Fb, s_b2c, wave, lane);
#pragma unroll
            for (int ks = 0; ks < 4; ks++) {
                short8 a = wfrag(wG2, 4, wave, ks, lane);
                short8 b0, b1;
                ldb(B1a, ks * 32, lane, b0, b1); mfma2(Fa, a, b0, b1);
                ldb(B1b, ks * 32, lane, b0, b1); mfma2(Fb, a, b0, b1);
            }
            storeF1(Fa, B2a, wave, lane, 1);
            storeF1(Fb, B2b, wave, lane, 1);
        }
        __syncthreads();

        // ---- G3: B2 @ W3 + b3 -> B1a/B1b (messages) ----
        {
            Frag1 Fa, Fb;
            initF1(Fa, s_b3c, wave, lane);
            initF1(Fb, s_b3c, wave, lane);
#pragma unroll
            for (int ks = 0; ks < 4; ks++) {
                short8 a = wfrag(wG3, 4, wave, ks, lane);
                short8 b0, b1;
                ldb(B2a, ks * 32, lane, b0, b1); mfma2(Fa, a, b0, b1);
                ldb(B2b, ks * 32, lane, b0, b1); mfma2(Fb, a, b0, b1);
            }
            storeF1(Fa, B1a, wave, lane, 0);
            storeF1(Fb, B1b, wave, lane, 0);
        }
        __syncthreads();

        // ---- fused E: V / [attn|coord] / edge-hidden for both i's (one ldb feeds 3 accums) ----
        {
            Frag1 FEa, FEb;
            initF1(FEa, s_be1, wave, lane);
            initF1(FEb, s_be1, wave, lane);
            {   // edge-hidden e-part (reads B0 cols 64..95 before overwrite)
                short8 a = wfrag(wE1, 5, wave, 4, lane);
                short8 b0, b1;
                ldb(B0a, 64, lane, b0, b1); mfma2(FEa, a, b0, b1);
                ldb(B0b, 64, lane, b0, b1); mfma2(FEb, a, b0, b1);
            }
            Frag1 FVa, FVb, FAa, FAb;
            initF1(FVa, s_bv, wave, lane);
            initF1(FVb, s_bv, wave, lane);
            initF1(FAa, s_bac, wave, lane);
            initF1(FAb, s_bac, wave, lane);
#pragma unroll
            for (int ks = 0; ks < 4; ks++) {
                short8 av = wfrag(wV, 4, wave, ks, lane);
                short8 aa = wfrag(wAC, 4, wave, ks, lane);
                short8 ae = wfrag(wE1, 5, wave, ks, lane);
                short8 b0, b1;
                ldb(B1a, ks * 32, lane, b0, b1);
                mfma2(FVa, av, b0, b1); mfma2(FAa, aa, b0, b1); mfma2(FEa, ae, b0, b1);
                ldb(B1b, ks * 32, lane, b0, b1);
                mfma2(FVb, av, b0, b1); mfma2(FAb, aa, b0, b1); mfma2(FEb, ae, b0, b1);
            }
            // B2 free since G3's barrier — store values early, drop their registers
            storeF1(FVa, B2a, wave, lane, 0);
            storeF1(FVb, B2b, wave, lane, 0);
            __syncthreads();   // all reads of B0/B1 done before overwrite
            storeF1(FAa, B0a, wave, lane, 1);   // [attn-hidden | coord-hidden]
            storeF1(FAb, B0b, wave, lane, 1);
            storeF1(FEa, B1a, wave, lane, 1);   // edge hidden
            storeF1(FEb, B1b, wave, lane, 1);
        }
        __syncthreads();

        // ---- edge LN (split) + attn logits (threads 256..511) ----
        if (t < 256) {
            ln_tile(B1a, s_eg, s_eb, t);
        } else {
            ln_tile(B1b, s_eg, s_eb, t - 256);
            int m = t - 256;
            int ii = m >> 7, mm = m & 127;
            const unsigned short* B0x = ii ? B0b : B0a;
            int j = mm >> 2, hh = mm & 3;
            float acc = s_ab2[hh];
#pragma unroll
            for (int m8 = 0; m8 < 8; m8++) {
                u16x8 r = *(u16x8*)(B0x + j * STR + m8 * 8);
#pragma unroll
                for (int i = 0; i < 8; i++) acc = fmaf(b2f(r[i]), s_aw2[hh][m8 * 8 + i], acc);
            }
            s_lg[ii][j][hh] = acc * 0.17677669529663687f;  // 1/sqrt(32)
        }
        __syncthreads();

        // ---- prefetch e residual (non-temporal; hides under softmax/edge2) ----
        const int ii9 = t >> 8, tt9 = t & 255;
        const int j9 = tt9 >> 3, sub9 = tt9 & 7;
        f32x4 ev = __builtin_nontemporal_load(
            (const f32x4*)(e + ((size_t)(biA + ii9) * NN + (j0 + j9)) * 32 + sub9 * 4));

        // ---- waves 0-3: online softmax + coord ; waves 4-7: edge2 GEMM ----
        if (wave < 4) {
            int ii = t >> 7, tt = t & 127;
            const unsigned short* B2x = ii ? B2b : B2a;
            int hh = tt >> 5;
#pragma unroll 4
            for (int j = 0; j < JT; j++) {
                float lg = s_lg[ii][j][hh];
                float nm = fmaxf(m_run, lg);
                float sc = __expf(m_run - nm);
                float p = __expf(lg - nm);
                float v = b2f(B2x[j * STR + tt]);
                acc_run = acc_run * sc + p * v;
                l_run = l_run * sc + p;
                m_run = nm;
            }
            if (tt < 32) {   // coord: t<32 -> A, t in [128,160) -> B
                const unsigned short* B0x = ii ? B0b : B0a;
                float acc = 0.f;
#pragma unroll
                for (int m = 0; m < 8; m++) {
                    u16x8 r = *(u16x8*)(B0x + tt * STR + 64 + m * 8);
#pragma unroll
                    for (int i = 0; i < 8; i++) acc = fmaf(b2f(r[i]), s_cw2[m * 8 + i], acc);
                }
                float cw = tanhf(acc * 0.1f);
                cu_x = fmaf(cw, xdn_x, cu_x);
                cu_y = fmaf(cw, xdn_y, cu_y);
            }
        } else {
            int w4 = wave - 4, ih = w4 >> 1, wv = w4 & 1;
            const unsigned short* B1x = ih ? B1b : B1a;
            unsigned short* e2x = ih ? s_e2b : s_e2a;
            int q = lane >> 4;
            f32x4 bb = *(const f32x4*)(s_be2 + wv * 16 + q * 4);
            f32x4 a0 = bb, a1 = bb;
#pragma unroll
            for (int ks = 0; ks < 4; ks++) {
                short8 b0, b1;
                ldb(B1x, ks * 32, lane, b0, b1);
                short8 aw = wfrag(wE2, 4, wv, ks, lane);
                a0 = __builtin_amdgcn_mfma_f32_16x16x32_bf16(aw, b0, a0, 0, 0, 0);
                a1 = __builtin_amdgcn_mfma_f32_16x16x32_bf16(aw, b1, a1, 0, 0, 0);
            }
#pragma unroll
            for (int ji = 0; ji < 2; ji++) {
                int j = ji * 16 + l15;
                int f0 = wv * 16 + q * 4;
                f32x4 v = ji ? a1 : a0;
                short4v p;
#pragma unroll
                for (int r = 0; r < 4; r++) p[r] = (short)f2b(v[r]);
                *(short4v*)(e2x + j * E2S + f0) = p;
            }
        }
        __syncthreads();

        // ---- e_new = LN(e + ee), write out non-temporal (ev prefetched) ----
        {
            const unsigned short* e2x = ii9 ? s_e2b : s_e2a;
            const unsigned short* p = e2x + j9 * E2S + sub9 * 4;
            float v0 = ev[0] + b2f(p[0]);
            float v1 = ev[1] + b2f(p[1]);
            float v2 = ev[2] + b2f(p[2]);
            float v3 = ev[3] + b2f(p[3]);
            float s = v0 + v1 + v2 + v3;
            s += __shfl_xor(s, 1); s += __shfl_xor(s, 2); s += __shfl_xor(s, 4);
            float mean = s * 0.03125f;
            float d0 = v0 - mean, d1 = v1 - mean, d2 = v2 - mean, d3 = v3 - mean;
            float sq = d0 * d0 + d1 * d1 + d2 * d2 + d3 * d3;
            sq += __shfl_xor(sq, 1); sq += __shfl_xor(sq, 2); sq += __shfl_xor(sq, 4);
            float rstd = rsqrtf(sq * 0.03125f + 1e-5f);
            f32x4 o;
            o[0] = d0 * rstd * s_eng[sub9 * 4 + 0] + s_enb[sub9 * 4 + 0];
            o[1] = d1 * rstd * s_eng[sub9 * 4 + 1] + s_enb[sub9 * 4 + 1];
            o[2] = d2 * rstd * s_eng[sub9 * 4 + 2] + s_enb[sub9 * 4 + 2];
            o[3] = d3 * rstd * s_eng[sub9 * 4 + 3] + s_enb[sub9 * 4 + 3];
            __builtin_nontemporal_store(o,
                (f32x4*)(out_e + ((size_t)(biA + ii9) * NN + (j0 + j9)) * 32 + sub9 * 4));
        }
    }

    // ================= node & coord epilogue (t<256 compute; all barriers uniform) =================
    float* s_ep = (float*)smA;    // tile buffers dead; need 896 floats
    float* s_hinA = s_ep;         // 192
    float* s_hinB = s_ep + 192;   // 192
    float* s_nhA  = s_ep + 384;   // 128
    float* s_nhB  = s_ep + 512;   // 128
    float* s_red  = s_ep + 640;   // 256

    __syncthreads();              // all LDS reads of last tile done
    if (t < 256) {
        int ii = t >> 7, tt = t & 127;
        (ii ? s_hinB : s_hinA)[64 + tt] = acc_run / l_run;   // messages_attended
    }
    if (t < 64) s_hinA[t] = s_hiA[t];
    else if (t < 128) s_hinB[t - 64] = s_hiB[t - 64];
    __syncthreads();

    if (t < 256) {
        int ii = t >> 7, tt = t & 127;
        const float* hin = ii ? s_hinB : s_hinA;
        float acc = node_b1[tt];
        for (int k4 = 0; k4 < 48; k4++) {
            f32x4 iv = *(const f32x4*)&hin[k4 * 4];
            acc = fmaf(iv[0], node_W1[(k4 * 4 + 0) * 128 + tt], acc);
            acc = fmaf(iv[1], node_W1[(k4 * 4 + 1) * 128 + tt], acc);
            acc = fmaf(iv[2], node_W1[(k4 * 4 + 2) * 128 + tt], acc);
            acc = fmaf(iv[3], node_W1[(k4 * 4 + 3) * 128 + tt], acc);
        }
        (ii ? s_nhB : s_nhA)[tt] = silu_f(acc);
    }
    __syncthreads();
    {
        int ii = t >> 7, tt = t & 127;
        float v = (t < 256) ? (ii ? s_nhB : s_nhA)[tt] : 0.f;
        float mean = half_sum512(v, s_red, t) * 0.0078125f;
        float d = (t < 256) ? (v - mean) : 0.f;
        float var = half_sum512(d * d, s_red, t) * 0.0078125f;
        float rstd = rsqrtf(var + 1e-5f);
        if (t < 256) (ii ? s_nhB : s_nhA)[tt] = d * rstd * node_ln_g[tt] + node_ln_b[tt];
    }
    __syncthreads();
    {
        int ii = t >> 7, tt = t & 127;
        float hv = 0.f;
        if (t < 256 && tt < 64) {
            const float* nh = ii ? s_nhB : s_nhA;
            float acc = node_b2[tt];
            for (int k4 = 0; k4 < 32; k4++) {
                f32x4 iv = *(const f32x4*)&nh[k4 * 4];
                acc = fmaf(iv[0], node_W2[(k4 * 4 + 0) * 64 + tt], acc);
                acc = fmaf(iv[1], node_W2[(k4 * 4 + 1) * 64 + tt], acc);
                acc = fmaf(iv[2], node_W2[(k4 * 4 + 2) * 64 + tt], acc);
                acc = fmaf(iv[3], node_W2[(k4 * 4 + 3) * 64 + tt], acc);
            }
            hv = acc + (ii ? s_hiB : s_hiA)[tt];
        }
        float mean = half_sum512((t < 256 && tt < 64) ? hv : 0.f, s_red, t) * 0.015625f;
        float d = (t < 256 && tt < 64) ? (hv - mean) : 0.f;
        float var = half_sum512(d * d, s_red, t) * 0.015625f;
        float rstd = rsqrtf(var + 1e-5f);
        if (t < 256 && tt < 64) out_h[(size_t)(biA + ii) * 64 + tt] = d * rstd * nn_g[tt] + nn_b[tt];
    }

    if (t < 256) {
        int tt = t & 127;
        if (tt < 32) {
            cu_x += __shfl_xor(cu_x, 16); cu_x += __shfl_xor(cu_x, 8);
            cu_x += __shfl_xor(cu_x, 4);  cu_x += __shfl_xor(cu_x, 2); cu_x += __shfl_xor(cu_x, 1);
            cu_y += __shfl_xor(cu_y, 16); cu_y += __shfl_xor(cu_y, 8);
            cu_y += __shfl_xor(cu_y, 4);  cu_y += __shfl_xor(cu_y, 2); cu_y += __shfl_xor(cu_y, 1);
            if (tt == 0) {
                float scl = coord_scale_p[0];
                if (t < 32) {
                    out_x[(size_t)biA * 2 + 0] = xiA0 + scl * cu_x;
                    out_x[(size_t)biA * 2 + 1] = xiA1 + scl * cu_y;
                } else {
                    out_x[(size_t)biB * 2 + 0] = xiB0 + scl * cu_x;
                    out_x[(size_t)biB * 2 + 1] = xiB1 + scl * cu_y;
                }
            }
        }
    }
}

extern "C" void kernel_launch(void* const* d_in, const int* in_sizes, int n_in,
                              void* d_out, int out_size, void* d_ws, size_t ws_size,
                              hipStream_t stream) {
    const float* h        = (const float*)d_in[0];
    const float* x        = (const float*)d_in[1];
    const float* e        = (const float*)d_in[2];
    const float* msg_W1   = (const float*)d_in[3];
    const float* msg_b1   = (const float*)d_in[4];
    const float* msg_ln_g = (const float*)d_in[5];
    const float* msg_ln_b = (const float*)d_in[6];
    const float* msg_W2   = (const float*)d_in[7];
    const float* msg_b2   = (const float*)d_in[8];
    const float* msg_W3   = (const float*)d_in[9];
    const float* msg_b3   = (const float*)d_in[10];
    const float* attn_W1  = (const float*)d_in[11];
    const float* attn_b1  = (const float*)d_in[12];
    const float* attn_W2  = (const float*)d_in[13];
    const float* attn_b2  = (const float*)d_in[14];
    const float* val_W    = (const float*)d_in[15];
    const float* val_b    = (const float*)d_in[16];
    const float* coord_W1 = (const float*)d_in[17];
    const float* coord_b1 = (const float*)d_in[18];
    const float* coord_W2 = (const float*)d_in[19];
    const float* node_W1  = (const float*)d_in[20];
    const float* node_b1  = (const float*)d_in[21];
    const float* node_ln_g= (const float*)d_in[22];
    const float* node_ln_b= (const float*)d_in[23];
    const float* node_W2  = (const float*)d_in[24];
    const float* node_b2  = (const float*)d_in[25];
    const float* edge_W1  = (const float*)d_in[26];
    const float* edge_b1  = (const float*)d_in[27];
    const float* edge_ln_g= (const float*)d_in[28];
    const float* edge_ln_b= (const float*)d_in[29];
    const float* edge_W2  = (const float*)d_in[30];
    const float* edge_b2  = (const float*)d_in[31];
    const float* nn_g     = (const float*)d_in[32];
    const float* nn_b     = (const float*)d_in[33];
    const float* en_g     = (const float*)d_in[34];
    const float* en_b     = (const float*)d_in[35];
    const float* coord_scale = (const float*)d_in[36];

    unsigned short* wpk = (unsigned short*)d_ws;

    float* out = (float*)d_out;
    float* out_h = out;
    float* out_x = out + (size_t)2 * 512 * 64;
    float* out_e = out_x + (size_t)2 * 512 * 2;

    hipLaunchKernelGGL(prepack_w, dim3((TOT_W + 255) / 256), dim3(256), 0, stream,
                       msg_W1, msg_W2, msg_W3, val_W, attn_W1, coord_W1, edge_W1, edge_W2, wpk);

    hipLaunchKernelGGL(egnn_mfma, dim3(512), dim3(512), 0, stream,
                       h, x, e,
                       msg_W1, msg_b1, msg_ln_g, msg_ln_b, msg_b2, msg_b3,
                       attn_b1, attn_W2, attn_b2, val_b, coord_b1, coord_W2,
                       node_W1, node_b1, node_ln_g, node_ln_b, node_W2, node_b2,
                       edge_b1, edge_ln_g, edge_ln_b, edge_b2,
                       nn_g, nn_b, en_g, en_b, coord_scale,
                       wpk, out_h, out_x, out_e);
}

// Round 13
// 642.869 us; speedup vs baseline: 1.0291x; 1.0291x over previous
//
#include <hip/hip_runtime.h>
#include <math.h>

typedef __attribute__((ext_vector_type(8))) short short8;
typedef __attribute__((ext_vector_type(4))) short short4v;
typedef __attribute__((ext_vector_type(8))) unsigned short u16x8;
typedef __attribute__((ext_vector_type(4))) float f32x4;

#define NN 512
#define JT 32
#define STR 136            // LDS row stride (bf16 elems): 272B, 16B-aligned, 2-way bank aliasing only
#define BUFSZ (JT * STR)   // 4352 ushorts = 8704 B per buffer
#define E2S 36             // stride of small edge2 output buffer

#define TOT_W 106496       // prepacked weight elements (bf16)

// Native bf16 conversion (RNE) — lowers to gfx950 HW cvt.
__device__ __forceinline__ unsigned short f2b(float x) {
    return __builtin_bit_cast(unsigned short, (__bf16)x);
}
__device__ __forceinline__ float b2f(unsigned short v) {
    return __uint_as_float(((unsigned int)v) << 16);
}
__device__ __forceinline__ float silu_f(float v) { return v / (1.f + __expf(-v)); }

// 512-thread-safe dual half reduction: threads 0..255 hold data (two independent
// 128-value sums: t<128 -> A, 128<=t<256 -> B); threads >=256 just hit barriers.
__device__ __forceinline__ float half_sum512(float v, float* s_red, int t) {
    if (t < 256) s_red[t] = v;
    __syncthreads();
    int tt = t & 127;
    for (int s = 64; s > 0; s >>= 1) {
        if (t < 256 && tt < s) s_red[t] += s_red[t + s];
        __syncthreads();
    }
    float r = (t < 256) ? s_red[t & 128] : 0.f;
    __syncthreads();
    return r;
}

// -------- weight prepack: fp32 -> bf16 A-operand fragments --------
// frag element: ws[(((ft*nK+ks)*64 + lane)*8 + jj)] = W[k][f],
//   k = ks*32 + (lane>>4)*8 + jj ; f = ft*16 + (lane&15)
__device__ __forceinline__ void frag_kf(int loc, int nK, int& k, int& f) {
    int jj = loc & 7;
    int lane = (loc >> 3) & 63;
    int fs = loc >> 9;
    int ks = fs % nK;
    int ft = fs / nK;
    k = ks * 32 + ((lane >> 4) << 3) + jj;
    f = ft * 16 + (lane & 15);
}

extern "C" __global__ void prepack_w(const float* __restrict__ msg_W1, const float* __restrict__ msg_W2,
                                     const float* __restrict__ msg_W3, const float* __restrict__ val_W,
                                     const float* __restrict__ attn_W1, const float* __restrict__ coord_W1,
                                     const float* __restrict__ edge_W1, const float* __restrict__ edge_W2,
                                     unsigned short* __restrict__ ws) {
    int idx = blockIdx.x * 256 + threadIdx.x;
    if (idx >= TOT_W) return;
    float v;
    int k, f;
    if (idx < 16384) {            // G1: msg_input-without-h_i @ W1 : rows [h_j(64)|e(32)|dist(1)|pad]
        frag_kf(idx, 4, k, f);
        v = (k <= 96) ? msg_W1[(64 + k) * 128 + f] : 0.f;
    } else if (idx < 32768) {     // G2
        frag_kf(idx - 16384, 4, k, f);
        v = msg_W2[k * 128 + f];
    } else if (idx < 49152) {     // G3
        frag_kf(idx - 32768, 4, k, f);
        v = msg_W3[k * 128 + f];
    } else if (idx < 65536) {     // val
        frag_kf(idx - 49152, 4, k, f);
        v = val_W[k * 128 + f];
    } else if (idx < 81920) {     // ac = [attn_W1 | coord_W1]
        frag_kf(idx - 65536, 4, k, f);
        v = (f < 64) ? attn_W1[k * 64 + f] : coord_W1[k * 64 + (f - 64)];
    } else if (idx < 102400) {    // edge_W1: ks 0..3 = msg part (rows 32..159), ks 4 = e part (rows 0..31)
        frag_kf(idx - 81920, 5, k, f);
        v = (k < 128) ? edge_W1[(32 + k) * 128 + f] : edge_W1[(k - 128) * 128 + f];
    } else {                      // edge_W2 (32 out)
        frag_kf(idx - 102400, 4, k, f);
        v = edge_W2[k * 32 + f];
    }
    ws[idx] = f2b(v);
}

// -------- MFMA helpers (one 16-wide f-tile per wave) --------
struct Frag1 { f32x4 a[2]; };   // two j-halves

__device__ __forceinline__ short8 wfrag(const unsigned short* base, int nK, int ft, int ks, int lane) {
    return *(const short8*)(base + (((ft * nK + ks) << 9) + (lane << 3)));
}

__device__ __forceinline__ void initF1(Frag1& F, const float* bias, int ft, int lane) {
    int q = lane >> 4;
    f32x4 bv = *(const f32x4*)(bias + ft * 16 + q * 4);
    F.a[0] = bv; F.a[1] = bv;
}

__device__ __forceinline__ void ldb(const unsigned short* B, int kcol, int lane, short8& b0, short8& b1) {
    int q8 = ((lane >> 4) << 3), l15 = lane & 15;
    b0 = *(const short8*)(B + l15 * STR + kcol + q8);
    b1 = *(const short8*)(B + (16 + l15) * STR + kcol + q8);
}

__device__ __forceinline__ void mfma2(Frag1& F, short8 a, short8 b0, short8 b1) {
    F.a[0] = __builtin_amdgcn_mfma_f32_16x16x32_bf16(a, b0, F.a[0], 0, 0, 0);
    F.a[1] = __builtin_amdgcn_mfma_f32_16x16x32_bf16(a, b1, F.a[1], 0, 0, 0);
}

__device__ __forceinline__ void storeF1(const Frag1& F, unsigned short* dbuf, int ft, int lane, int act) {
    int q = lane >> 4, l15 = lane & 15;
#pragma unroll
    for (int ji = 0; ji < 2; ji++) {
        int j = ji * 16 + l15;
        int f0 = ft * 16 + q * 4;
        f32x4 v = F.a[ji];
        short4v p;
#pragma unroll
        for (int r = 0; r < 4; r++) {
            float o = act ? silu_f(v[r]) : v[r];
            p[r] = (short)f2b(o);
        }
        *(short4v*)(dbuf + j * STR + f0) = p;
    }
}

// LayerNorm over 128 features (bf16 rows, fp32 math). tt in [0,256): j=tt>>3, sub=tt&7.
__device__ __forceinline__ void ln_tile(unsigned short* buf, const float* g, const float* bv, int tt) {
    int j = tt >> 3, sub = tt & 7;
    unsigned short* p = buf + j * STR + sub * 16;
    u16x8 r0 = *(u16x8*)p;
    u16x8 r1 = *(u16x8*)(p + 8);
    float v[16];
#pragma unroll
    for (int i = 0; i < 8; i++) { v[i] = b2f(r0[i]); v[8 + i] = b2f(r1[i]); }
    float sm = 0.f;
#pragma unroll
    for (int i = 0; i < 16; i++) sm += v[i];
    sm += __shfl_xor(sm, 1); sm += __shfl_xor(sm, 2); sm += __shfl_xor(sm, 4);
    float mean = sm * 0.0078125f;
    float sq = 0.f;
#pragma unroll
    for (int i = 0; i < 16; i++) { float d = v[i] - mean; sq += d * d; }
    sq += __shfl_xor(sq, 1); sq += __shfl_xor(sq, 2); sq += __shfl_xor(sq, 4);
    float rstd = rsqrtf(sq * 0.0078125f + 1e-5f);
    u16x8 o0, o1;
#pragma unroll
    for (int i = 0; i < 8; i++) {
        o0[i] = f2b((v[i] - mean) * rstd * g[sub * 16 + i] + bv[sub * 16 + i]);
        o1[i] = f2b((v[8 + i] - mean) * rstd * g[sub * 16 + 8 + i] + bv[sub * 16 + 8 + i]);
    }
    *(u16x8*)p = o0;
    *(u16x8*)(p + 8) = o1;
}

// =====================================================================
// 2 i-nodes per block, 512 threads (8 waves, ft = wave): grid 512 =
// 2 blocks/CU (66 KB LDS), 4 waves/SIMD. softmax (waves 0-3) concurrent
// with edge2 GEMM (waves 4-7). Native bf16 conversions (HW cvt).
// Best-verified configuration (Round 10: 514.5 us).
// =====================================================================
extern "C" __global__ __launch_bounds__(512, 4)
void egnn_mfma(const float* __restrict__ h, const float* __restrict__ x, const float* __restrict__ e,
               const float* __restrict__ msg_W1, const float* __restrict__ msg_b1,
               const float* __restrict__ msg_ln_g, const float* __restrict__ msg_ln_b,
               const float* __restrict__ msg_b2, const float* __restrict__ msg_b3,
               const float* __restrict__ attn_b1, const float* __restrict__ attn_W2,
               const float* __restrict__ attn_b2, const float* __restrict__ val_b,
               const float* __restrict__ coord_b1, const float* __restrict__ coord_W2,
               const float* __restrict__ node_W1, const float* __restrict__ node_b1,
               const float* __restrict__ node_ln_g, const float* __restrict__ node_ln_b,
               const float* __restrict__ node_W2, const float* __restrict__ node_b2,
               const float* __restrict__ edge_b1, const float* __restrict__ edge_ln_g,
               const float* __restrict__ edge_ln_b, const float* __restrict__ edge_b2,
               const float* __restrict__ nn_g, const float* __restrict__ nn_b,
               const float* __restrict__ en_g, const float* __restrict__ en_b,
               const float* __restrict__ coord_scale_p,
               const unsigned short* __restrict__ wpk,
               float* __restrict__ out_h, float* __restrict__ out_x, float* __restrict__ out_e) {
    const int t = threadIdx.x;
    const int wave = t >> 6, lane = t & 63;
    const int biA = blockIdx.x * 2;
    const int biB = biA + 1;
    const int b = biA >> 9;

    __shared__ __align__(16) unsigned short smA[3 * BUFSZ];
    __shared__ __align__(16) unsigned short smB[3 * BUFSZ];
    unsigned short* B0a = smA;
    unsigned short* B1a = smA + BUFSZ;
    unsigned short* B2a = smA + 2 * BUFSZ;
    unsigned short* B0b = smB;
    unsigned short* B1b = smB + BUFSZ;
    unsigned short* B2b = smB + 2 * BUFSZ;
    __shared__ __align__(16) unsigned short s_e2a[32 * E2S];
    __shared__ __align__(16) unsigned short s_e2b[32 * E2S];

    __shared__ __align__(16) float s_bias1a[128], s_bias1b[128];
    __shared__ __align__(16) float s_b2c[128], s_b3c[128], s_bv[128], s_bac[128], s_be1[128];
    __shared__ __align__(16) float s_be2[32];
    __shared__ __align__(16) float s_mg[128], s_mb[128], s_eg[128], s_eb[128];
    __shared__ __align__(16) float s_cw2[64], s_aw2[4][64], s_ab2[4], s_eng[32], s_enb[32];
    __shared__ __align__(16) float s_lg[2][JT][4];
    __shared__ __align__(16) float s_hiA[64], s_hiB[64];

    const unsigned short* wG1 = wpk;
    const unsigned short* wG2 = wpk + 16384;
    const unsigned short* wG3 = wpk + 32768;
    const unsigned short* wV  = wpk + 49152;
    const unsigned short* wAC = wpk + 65536;
    const unsigned short* wE1 = wpk + 81920;
    const unsigned short* wE2 = wpk + 102400;

    // ---- stage params ----
    if (t < 64) s_hiA[t] = h[(size_t)biA * 64 + t];
    else if (t < 128) s_hiB[t - 64] = h[(size_t)biB * 64 + (t - 64)];
    if (t < 128) {
        s_b2c[t] = msg_b2[t]; s_b3c[t] = msg_b3[t]; s_bv[t] = val_b[t];
        s_bac[t] = (t < 64) ? attn_b1[t] : coord_b1[t - 64];
        s_be1[t] = edge_b1[t];
        s_mg[t] = msg_ln_g[t]; s_mb[t] = msg_ln_b[t];
        s_eg[t] = edge_ln_g[t]; s_eb[t] = edge_ln_b[t];
    }
    if (t < 32) { s_be2[t] = edge_b2[t]; s_eng[t] = en_g[t]; s_enb[t] = en_b[t]; }
    if (t < 64) s_cw2[t] = coord_W2[t];
    if (t < 256) { int hh = t >> 6, k = t & 63; s_aw2[hh][k] = attn_W2[k * 4 + hh]; }
    if (t < 4) s_ab2[t] = attn_b2[t];
    __syncthreads();
    // bias1' = msg_b1 + h_i @ W1[0:64]  (fp32, exact) — per i
    if (t < 256) {
        int ii = t >> 7, tt = t & 127;
        const float* hi = ii ? s_hiB : s_hiA;
        float acc = msg_b1[tt];
        for (int k = 0; k < 64; k++) acc = fmaf(hi[k], msg_W1[k * 128 + tt], acc);
        (ii ? s_bias1b : s_bias1a)[tt] = acc;
    }
    const float xiA0 = x[(size_t)biA * 2 + 0];
    const float xiA1 = x[(size_t)biA * 2 + 1];
    const float xiB0 = x[(size_t)biB * 2 + 0];
    const float xiB1 = x[(size_t)biB * 2 + 1];

    float m_run = -3e38f, l_run = 0.f, acc_run = 0.f;   // t<256 only: i=t>>7, f=t&127
    float cu_x = 0.f, cu_y = 0.f, xdn_x = 0.f, xdn_y = 0.f;

    const int l15 = lane & 15;

#pragma unroll 1
    for (int j0 = 0; j0 < NN; j0 += JT) {
        // ---- stage: half 0 -> h (+zeros), half 1 -> eA/eB (non-temporal e) ----
        {
            int half = t >> 8, tt = t & 255;
            int j = tt >> 3, sub = tt & 7;
            int jj = j0 + j;
            if (half == 0) {
                const float* hp = h + ((size_t)(b * NN + jj)) * 64 + sub * 8;
                float4 h0 = *(const float4*)hp;
                float4 h1 = *(const float4*)(hp + 4);
                u16x8 o;
                o[0] = f2b(h0.x); o[1] = f2b(h0.y); o[2] = f2b(h0.z); o[3] = f2b(h0.w);
                o[4] = f2b(h1.x); o[5] = f2b(h1.y); o[6] = f2b(h1.z); o[7] = f2b(h1.w);
                *(u16x8*)(B0a + j * STR + sub * 8) = o;        // h shared: only in B0a
                u16x8 z = (u16x8)0;
                if (sub > 4)       *(u16x8*)(B0a + j * STR + 96 + (sub - 4) * 8) = z;  // 104..127
                else if (sub >= 1) *(u16x8*)(B0b + j * STR + 96 + sub * 8) = z;        // 104..127
            } else {
                if (sub < 4) {
                    const f32x4* ea = (const f32x4*)(e + ((size_t)biA * NN + jj) * 32 + sub * 8);
                    f32x4 e0 = __builtin_nontemporal_load(ea);
                    f32x4 e1 = __builtin_nontemporal_load(ea + 1);
                    u16x8 oe;
                    oe[0] = f2b(e0[0]); oe[1] = f2b(e0[1]); oe[2] = f2b(e0[2]); oe[3] = f2b(e0[3]);
                    oe[4] = f2b(e1[0]); oe[5] = f2b(e1[1]); oe[6] = f2b(e1[2]); oe[7] = f2b(e1[3]);
                    *(u16x8*)(B0a + j * STR + 64 + sub * 8) = oe;
                } else {
                    const f32x4* eb = (const f32x4*)(e + ((size_t)biB * NN + jj) * 32 + (sub - 4) * 8);
                    f32x4 e0 = __builtin_nontemporal_load(eb);
                    f32x4 e1 = __builtin_nontemporal_load(eb + 1);
                    u16x8 oe;
                    oe[0] = f2b(e0[0]); oe[1] = f2b(e0[1]); oe[2] = f2b(e0[2]); oe[3] = f2b(e0[3]);
                    oe[4] = f2b(e1[0]); oe[5] = f2b(e1[1]); oe[6] = f2b(e1[2]); oe[7] = f2b(e1[3]);
                    *(u16x8*)(B0b + j * STR + 64 + (sub - 4) * 8) = oe;
                }
            }
        }
        if (t < JT) {                    // dist for i=A (these threads also own coord state for A)
            int jj = j0 + t;
            float dx = x[(size_t)(b * NN + jj) * 2 + 0] - xiA0;
            float dy = x[(size_t)(b * NN + jj) * 2 + 1] - xiA1;
            float dist = sqrtf(dx * dx + dy * dy);
            float inv = 1.f / (dist + 1e-8f);
            xdn_x = dx * inv; xdn_y = dy * inv;
            u16x8 z = (u16x8)0;
            z[0] = f2b(dist);
            *(u16x8*)(B0a + t * STR + 96) = z;                 // dist + zeros 97..103
        } else if (t >= 128 && t < 128 + JT) {   // dist for i=B
            int tb = t - 128;
            int jj = j0 + tb;
            float dx = x[(size_t)(b * NN + jj) * 2 + 0] - xiB0;
            float dy = x[(size_t)(b * NN + jj) * 2 + 1] - xiB1;
            float dist = sqrtf(dx * dx + dy * dy);
            float inv = 1.f / (dist + 1e-8f);
            xdn_x = dx * inv; xdn_y = dy * inv;
            u16x8 z = (u16x8)0;
            z[0] = f2b(dist);
            *(u16x8*)(B0b + tb * STR + 96) = z;
        }
        __syncthreads();

        // ---- G1: silu([h_j|e|dist] @ W1' + bias1') -> B1a/B1b (h-part from B0a for both) ----
        {
            Frag1 Fa, Fb;
            initF1(Fa, s_bias1a, wave, lane);
            initF1(Fb, s_bias1b, wave, lane);
#pragma unroll
            for (int ks = 0; ks < 4; ks++) {
                short8 a = wfrag(wG1, 4, wave, ks, lane);
                short8 b0, b1;
                ldb(B0a, ks * 32, lane, b0, b1);
                mfma2(Fa, a, b0, b1);
                if (ks >= 2) ldb(B0b, ks * 32, lane, b0, b1);   // e/dist region differs per i
                mfma2(Fb, a, b0, b1);
            }
            storeF1(Fa, B1a, wave, lane, 1);
            storeF1(Fb, B1b, wave, lane, 1);
        }
        __syncthreads();
        if (t < 256) ln_tile(B1a, s_mg, s_mb, t);
        else         ln_tile(B1b, s_mg, s_mb, t - 256);
        __syncthreads();

        // ---- G2: silu(B1 @ W2 + b2) -> B2a/B2b ----
        {
            Frag1 Fa, Fb;
            initF1(Fa, s_b2c, wave, lane);
            initF1(Fb, s_b2c, wave, lane);
#pragma unroll
            for (int ks = 0; ks < 4; ks++) {
                short8 a = wfrag(wG2, 4, wave, ks, lane);
                short8 b0, b1;
                ldb(B1a, ks * 32, lane, b0, b1); mfma2(Fa, a, b0, b1);
                ldb(B1b, ks * 32, lane, b0, b1); mfma2(Fb, a, b0, b1);
            }
            storeF1(Fa, B2a, wave, lane, 1);
            storeF1(Fb, B2b, wave, lane, 1);
        }
        __syncthreads();

        // ---- G3: B2 @ W3 + b3 -> B1a/B1b (messages) ----
        {
            Frag1 Fa, Fb;
            initF1(Fa, s_b3c, wave, lane);
            initF1(Fb, s_b3c, wave, lane);
#pragma unroll
            for (int ks = 0; ks < 4; ks++) {
                short8 a = wfrag(wG3, 4, wave, ks, lane);
                short8 b0, b1;
                ldb(B2a, ks * 32, lane, b0, b1); mfma2(Fa, a, b0, b1);
                ldb(B2b, ks * 32, lane, b0, b1); mfma2(Fb, a, b0, b1);
            }
            storeF1(Fa, B1a, wave, lane, 0);
            storeF1(Fb, B1b, wave, lane, 0);
        }
        __syncthreads();

        // ---- fused E: V / [attn|coord] / edge-hidden for both i's (one ldb feeds 3 accums) ----
        {
            Frag1 FEa, FEb;
            initF1(FEa, s_be1, wave, lane);
            initF1(FEb, s_be1, wave, lane);
            {   // edge-hidden e-part (reads B0 cols 64..95 before overwrite)
                short8 a = wfrag(wE1, 5, wave, 4, lane);
                short8 b0, b1;
                ldb(B0a, 64, lane, b0, b1); mfma2(FEa, a, b0, b1);
                ldb(B0b, 64, lane, b0, b1); mfma2(FEb, a, b0, b1);
            }
            Frag1 FVa, FVb, FAa, FAb;
            initF1(FVa, s_bv, wave, lane);
            initF1(FVb, s_bv, wave, lane);
            initF1(FAa, s_bac, wave, lane);
            initF1(FAb, s_bac, wave, lane);
#pragma unroll
            for (int ks = 0; ks < 4; ks++) {
                short8 av = wfrag(wV, 4, wave, ks, lane);
                short8 aa = wfrag(wAC, 4, wave, ks, lane);
                short8 ae = wfrag(wE1, 5, wave, ks, lane);
                short8 b0, b1;
                ldb(B1a, ks * 32, lane, b0, b1);
                mfma2(FVa, av, b0, b1); mfma2(FAa, aa, b0, b1); mfma2(FEa, ae, b0, b1);
                ldb(B1b, ks * 32, lane, b0, b1);
                mfma2(FVb, av, b0, b1); mfma2(FAb, aa, b0, b1); mfma2(FEb, ae, b0, b1);
            }
            // B2 free since G3's barrier — store values early, drop their registers
            storeF1(FVa, B2a, wave, lane, 0);
            storeF1(FVb, B2b, wave, lane, 0);
            __syncthreads();   // all reads of B0/B1 done before overwrite
            storeF1(FAa, B0a, wave, lane, 1);   // [attn-hidden | coord-hidden]
            storeF1(FAb, B0b, wave, lane, 1);
            storeF1(FEa, B1a, wave, lane, 1);   // edge hidden
            storeF1(FEb, B1b, wave, lane, 1);
        }
        __syncthreads();

        // ---- edge LN (split) + attn logits (threads 256..511) ----
        if (t < 256) {
            ln_tile(B1a, s_eg, s_eb, t);
        } else {
            ln_tile(B1b, s_eg, s_eb, t - 256);
            int m = t - 256;
            int ii = m >> 7, mm = m & 127;
            const unsigned short* B0x = ii ? B0b : B0a;
            int j = mm >> 2, hh = mm & 3;
            float acc = s_ab2[hh];
#pragma unroll
            for (int m8 = 0; m8 < 8; m8++) {
                u16x8 r = *(u16x8*)(B0x + j * STR + m8 * 8);
#pragma unroll
                for (int i = 0; i < 8; i++) acc = fmaf(b2f(r[i]), s_aw2[hh][m8 * 8 + i], acc);
            }
            s_lg[ii][j][hh] = acc * 0.17677669529663687f;  // 1/sqrt(32)
        }
        __syncthreads();

        // ---- prefetch e residual (non-temporal; hides under softmax/edge2) ----
        const int ii9 = t >> 8, tt9 = t & 255;
        const int j9 = tt9 >> 3, sub9 = tt9 & 7;
        f32x4 ev = __builtin_nontemporal_load(
            (const f32x4*)(e + ((size_t)(biA + ii9) * NN + (j0 + j9)) * 32 + sub9 * 4));

        // ---- waves 0-3: online softmax + coord ; waves 4-7: edge2 GEMM ----
        if (wave < 4) {
            int ii = t >> 7, tt = t & 127;
            const unsigned short* B2x = ii ? B2b : B2a;
            int hh = tt >> 5;
#pragma unroll 4
            for (int j = 0; j < JT; j++) {
                float lg = s_lg[ii][j][hh];
                float nm = fmaxf(m_run, lg);
                float sc = __expf(m_run - nm);
                float p = __expf(lg - nm);
                float v = b2f(B2x[j * STR + tt]);
                acc_run = acc_run * sc + p * v;
                l_run = l_run * sc + p;
                m_run = nm;
            }
            if (tt < 32) {   // coord: t<32 -> A, t in [128,160) -> B
                const unsigned short* B0x = ii ? B0b : B0a;
                float acc = 0.f;
#pragma unroll
                for (int m = 0; m < 8; m++) {
                    u16x8 r = *(u16x8*)(B0x + tt * STR + 64 + m * 8);
#pragma unroll
                    for (int i = 0; i < 8; i++) acc = fmaf(b2f(r[i]), s_cw2[m * 8 + i], acc);
                }
                float cw = tanhf(acc * 0.1f);
                cu_x = fmaf(cw, xdn_x, cu_x);
                cu_y = fmaf(cw, xdn_y, cu_y);
            }
        } else {
            int w4 = wave - 4, ih = w4 >> 1, wv = w4 & 1;
            const unsigned short* B1x = ih ? B1b : B1a;
            unsigned short* e2x = ih ? s_e2b : s_e2a;
            int q = lane >> 4;
            f32x4 bb = *(const f32x4*)(s_be2 + wv * 16 + q * 4);
            f32x4 a0 = bb, a1 = bb;
#pragma unroll
            for (int ks = 0; ks < 4; ks++) {
                short8 b0, b1;
                ldb(B1x, ks * 32, lane, b0, b1);
                short8 aw = wfrag(wE2, 4, wv, ks, lane);
                a0 = __builtin_amdgcn_mfma_f32_16x16x32_bf16(aw, b0, a0, 0, 0, 0);
                a1 = __builtin_amdgcn_mfma_f32_16x16x32_bf16(aw, b1, a1, 0, 0, 0);
            }
#pragma unroll
            for (int ji = 0; ji < 2; ji++) {
                int j = ji * 16 + l15;
                int f0 = wv * 16 + q * 4;
                f32x4 v = ji ? a1 : a0;
                short4v p;
#pragma unroll
                for (int r = 0; r < 4; r++) p[r] = (short)f2b(v[r]);
                *(short4v*)(e2x + j * E2S + f0) = p;
            }
        }
        __syncthreads();

        // ---- e_new = LN(e + ee), write out non-temporal (ev prefetched) ----
        {
            const unsigned short* e2x = ii9 ? s_e2b : s_e2a;
            const unsigned short* p = e2x + j9 * E2S + sub9 * 4;
            float v0 = ev[0] + b2f(p[0]);
            float v1 = ev[1] + b2f(p[1]);
            float v2 = ev[2] + b2f(p[2]);
            float v3 = ev[3] + b2f(p[3]);
            float s = v0 + v1 + v2 + v3;
            s += __shfl_xor(s, 1); s += __shfl_xor(s, 2); s += __shfl_xor(s, 4);
            float mean = s * 0.03125f;
            float d0 = v0 - mean, d1 = v1 - mean, d2 = v2 - mean, d3 = v3 - mean;
            float sq = d0 * d0 + d1 * d1 + d2 * d2 + d3 * d3;
            sq += __shfl_xor(sq, 1); sq += __shfl_xor(sq, 2); sq += __shfl_xor(sq, 4);
            float rstd = rsqrtf(sq * 0.03125f + 1e-5f);
            f32x4 o;
            o[0] = d0 * rstd * s_eng[sub9 * 4 + 0] + s_enb[sub9 * 4 + 0];
            o[1] = d1 * rstd * s_eng[sub9 * 4 + 1] + s_enb[sub9 * 4 + 1];
            o[2] = d2 * rstd * s_eng[sub9 * 4 + 2] + s_enb[sub9 * 4 + 2];
            o[3] = d3 * rstd * s_eng[sub9 * 4 + 3] + s_enb[sub9 * 4 + 3];
            __builtin_nontemporal_store(o,
                (f32x4*)(out_e + ((size_t)(biA + ii9) * NN + (j0 + j9)) * 32 + sub9 * 4));
        }
    }

    // ================= node & coord epilogue (t<256 compute; all barriers uniform) =================
    float* s_ep = (float*)smA;    // tile buffers dead; need 896 floats
    float* s_hinA = s_ep;         // 192
    float* s_hinB = s_ep + 192;   // 192
    float* s_nhA  = s_ep + 384;   // 128
    float* s_nhB  = s_ep + 512;   // 128
    float* s_red  = s_ep + 640;   // 256

    __syncthreads();              // all LDS reads of last tile done
    if (t < 256) {
        int ii = t >> 7, tt = t & 127;
        (ii ? s_hinB : s_hinA)[64 + tt] = acc_run / l_run;   // messages_attended
    }
    if (t < 64) s_hinA[t] = s_hiA[t];
    else if (t < 128) s_hinB[t - 64] = s_hiB[t - 64];
    __syncthreads();

    if (t < 256) {
        int ii = t >> 7, tt = t & 127;
        const float* hin = ii ? s_hinB : s_hinA;
        float acc = node_b1[tt];
        for (int k4 = 0; k4 < 48; k4++) {
            f32x4 iv = *(const f32x4*)&hin[k4 * 4];
            acc = fmaf(iv[0], node_W1[(k4 * 4 + 0) * 128 + tt], acc);
            acc = fmaf(iv[1], node_W1[(k4 * 4 + 1) * 128 + tt], acc);
            acc = fmaf(iv[2], node_W1[(k4 * 4 + 2) * 128 + tt], acc);
            acc = fmaf(iv[3], node_W1[(k4 * 4 + 3) * 128 + tt], acc);
        }
        (ii ? s_nhB : s_nhA)[tt] = silu_f(acc);
    }
    __syncthreads();
    {
        int ii = t >> 7, tt = t & 127;
        float v = (t < 256) ? (ii ? s_nhB : s_nhA)[tt] : 0.f;
        float mean = half_sum512(v, s_red, t) * 0.0078125f;
        float d = (t < 256) ? (v - mean) : 0.f;
        float var = half_sum512(d * d, s_red, t) * 0.0078125f;
        float rstd = rsqrtf(var + 1e-5f);
        if (t < 256) (ii ? s_nhB : s_nhA)[tt] = d * rstd * node_ln_g[tt] + node_ln_b[tt];
    }
    __syncthreads();
    {
        int ii = t >> 7, tt = t & 127;
        float hv = 0.f;
        if (t < 256 && tt < 64) {
            const float* nh = ii ? s_nhB : s_nhA;
            float acc = node_b2[tt];
            for (int k4 = 0; k4 < 32; k4++) {
                f32x4 iv = *(const f32x4*)&nh[k4 * 4];
                acc = fmaf(iv[0], node_W2[(k4 * 4 + 0) * 64 + tt], acc);
                acc = fmaf(iv[1], node_W2[(k4 * 4 + 1) * 64 + tt], acc);
                acc = fmaf(iv[2], node_W2[(k4 * 4 + 2) * 64 + tt], acc);
                acc = fmaf(iv[3], node_W2[(k4 * 4 + 3) * 64 + tt], acc);
            }
            hv = acc + (ii ? s_hiB : s_hiA)[tt];
        }
        float mean = half_sum512((t < 256 && tt < 64) ? hv : 0.f, s_red, t) * 0.015625f;
        float d = (t < 256 && tt < 64) ? (hv - mean) : 0.f;
        float var = half_sum512(d * d, s_red, t) * 0.015625f;
        float rstd = rsqrtf(var + 1e-5f);
        if (t < 256 && tt < 64) out_h[(size_t)(biA + ii) * 64 + tt] = d * rstd * nn_g[tt] + nn_b[tt];
    }

    if (t < 256) {
        int tt = t & 127;
        if (tt < 32) {
            cu_x += __shfl_xor(cu_x, 16); cu_x += __shfl_xor(cu_x, 8);
            cu_x += __shfl_xor(cu_x, 4);  cu_x += __shfl_xor(cu_x, 2); cu_x += __shfl_xor(cu_x, 1);
            cu_y += __shfl_xor(cu_y, 16); cu_y += __shfl_xor(cu_y, 8);
            cu_y += __shfl_xor(cu_y, 4);  cu_y += __shfl_xor(cu_y, 2); cu_y += __shfl_xor(cu_y, 1);
            if (tt == 0) {
                float scl = coord_scale_p[0];
                if (t < 32) {
                    out_x[(size_t)biA * 2 + 0] = xiA0 + scl * cu_x;
                    out_x[(size_t)biA * 2 + 1] = xiA1 + scl * cu_y;
                } else {
                    out_x[(size_t)biB * 2 + 0] = xiB0 + scl * cu_x;
                    out_x[(size_t)biB * 2 + 1] = xiB1 + scl * cu_y;
                }
            }
        }
    }
}

extern "C" void kernel_launch(void* const* d_in, const int* in_sizes, int n_in,
                              void* d_out, int out_size, void* d_ws, size_t ws_size,
                              hipStream_t stream) {
    const float* h        = (const float*)d_in[0];
    const float* x        = (const float*)d_in[1];
    const float* e        = (const float*)d_in[2];
    const float* msg_W1   = (const float*)d_in[3];
    const float* msg_b1   = (const float*)d_in[4];
    const float* msg_ln_g = (const float*)d_in[5];
    const float* msg_ln_b = (const float*)d_in[6];
    const float* msg_W2   = (const float*)d_in[7];
    const float* msg_b2   = (const float*)d_in[8];
    const float* msg_W3   = (const float*)d_in[9];
    const float* msg_b3   = (const float*)d_in[10];
    const float* attn_W1  = (const float*)d_in[11];
    const float* attn_b1  = (const float*)d_in[12];
    const float* attn_W2  = (const float*)d_in[13];
    const float* attn_b2  = (const float*)d_in[14];
    const float* val_W    = (const float*)d_in[15];
    const float* val_b    = (const float*)d_in[16];
    const float* coord_W1 = (const float*)d_in[17];
    const float* coord_b1 = (const float*)d_in[18];
    const float* coord_W2 = (const float*)d_in[19];
    const float* node_W1  = (const float*)d_in[20];
    const float* node_b1  = (const float*)d_in[21];
    const float* node_ln_g= (const float*)d_in[22];
    const float* node_ln_b= (const float*)d_in[23];
    const float* node_W2  = (const float*)d_in[24];
    const float* node_b2  = (const float*)d_in[25];
    const float* edge_W1  = (const float*)d_in[26];
    const float* edge_b1  = (const float*)d_in[27];
    const float* edge_ln_g= (const float*)d_in[28];
    const float* edge_ln_b= (const float*)d_in[29];
    const float* edge_W2  = (const float*)d_in[30];
    const float* edge_b2  = (const float*)d_in[31];
    const float* nn_g     = (const float*)d_in[32];
    const float* nn_b     = (const float*)d_in[33];
    const float* en_g     = (const float*)d_in[34];
    const float* en_b     = (const float*)d_in[35];
    const float* coord_scale = (const float*)d_in[36];

    unsigned short* wpk = (unsigned short*)d_ws;

    float* out = (float*)d_out;
    float* out_h = out;
    float* out_x = out + (size_t)2 * 512 * 64;
    float* out_e = out_x + (size_t)2 * 512 * 2;

    hipLaunchKernelGGL(prepack_w, dim3((TOT_W + 255) / 256), dim3(256), 0, stream,
                       msg_W1, msg_W2, msg_W3, val_W, attn_W1, coord_W1, edge_W1, edge_W2, wpk);

    hipLaunchKernelGGL(egnn_mfma, dim3(512), dim3(512), 0, stream,
                       h, x, e,
                       msg_W1, msg_b1, msg_ln_g, msg_ln_b, msg_b2, msg_b3,
                       attn_b1, attn_W2, attn_b2, val_b, coord_b1, coord_W2,
                       node_W1, node_b1, node_ln_g, node_ln_b, node_W2, node_b2,
                       edge_b1, edge_ln_g, edge_ln_b, edge_b2,
                       nn_g, nn_b, en_g, en_b, coord_scale,
                       wpk, out_h, out_x, out_e);
}